// Round 3
// baseline (236.460 us; speedup 1.0000x reference)
//
#include <hip/hip_runtime.h>
#include <hip/hip_bf16.h>
#include <cstdint>

using bf16   = __bf16;
using bf16x4 = __attribute__((ext_vector_type(4))) __bf16;
using bf16x8 = __attribute__((ext_vector_type(8))) __bf16;
using f32x4  = __attribute__((ext_vector_type(4))) float;

#define MFMA16(a, b, c) __builtin_amdgcn_mfma_f32_16x16x32_bf16((a), (b), (c), 0, 0, 0)

// async global->LDS, 16B per lane; LDS dest = wave-uniform base + lane*16.
__device__ __forceinline__ void load_lds16(const bf16* g, bf16* l) {
    __builtin_amdgcn_global_load_lds(
        (const __attribute__((address_space(1))) void*)g,
        (__attribute__((address_space(3))) void*)l, 16, 0, 0);
}

// ---------------- fused cast fp32 -> bf16 (x, Wq*scale, Wk, Wv) ----------------
__global__ __launch_bounds__(256) void cast_all(const float* __restrict__ x,
                                                const float* __restrict__ Wq,
                                                const float* __restrict__ Wk,
                                                const float* __restrict__ Wv,
                                                bf16* __restrict__ xb,
                                                bf16* __restrict__ wb,
                                                float qscale) {
    int i = blockIdx.x * 256 + threadIdx.x;   // float4 index, 1835008 total
    const float* src; bf16* dst; int off; float scale = 1.0f;
    if (i < 1048576)      { src = x;  dst = xb;              off = i; }
    else if (i < 1310720) { src = Wq; dst = wb;              off = i - 1048576; scale = qscale; }
    else if (i < 1572864) { src = Wk; dst = wb + (1u << 20); off = i - 1310720; }
    else                  { src = Wv; dst = wb + (2u << 20); off = i - 1572864; }
    float4 v = reinterpret_cast<const float4*>(src)[off];
    bf16x4 o;
    o[0] = (bf16)(v.x * scale); o[1] = (bf16)(v.y * scale);
    o[2] = (bf16)(v.z * scale); o[3] = (bf16)(v.w * scale);
    reinterpret_cast<bf16x4*>(dst)[off] = o;
}

// ---------------- fused QKV projection: y = x @ [Wq|Wk|Wv]^T ----------------
// 128x128 tiles (m97 structure), BK=64 -> 768 blocks = 3/CU, acc 4x4 per wave.
// LDS[row][cc] = global[row][cc ^ (row&7)] (8-elem chunks, conflict-free readback)
__global__ __launch_bounds__(256) void qkv_gemm(const bf16* __restrict__ xb,
                                                const bf16* __restrict__ wb,
                                                bf16* __restrict__ Qo,
                                                bf16* __restrict__ Ko,
                                                bf16* __restrict__ Vt) {
    const int n0 = blockIdx.x * 128;
    const int m0 = blockIdx.y * 128;

    __shared__ __align__(16) bf16 As[128 * 64];   // 16 KB
    __shared__ __align__(16) bf16 Bs[128 * 64];   // 16 KB

    const int t    = threadIdx.x;
    const int lane = t & 63;
    const int wid  = t >> 6;
    const int quad = lane >> 4;
    const int col  = lane & 15;
    const int wm   = wid & 1;      // M half (64)
    const int wn   = wid >> 1;     // N half (64)

    const int rsub = lane >> 3;
    const int csw  = ((lane & 7) ^ rsub) * 8;

    f32x4 acc[4][4] = {};

    const bf16* Ag = &xb[(size_t)(m0 + rsub) * 1024 + csw];
    const bf16* Bg = &wb[(size_t)(n0 + rsub) * 1024 + csw];

    for (int kc = 0; kc < 1024; kc += 64) {
        __syncthreads();
#pragma unroll
        for (int j = 0; j < 4; ++j) {
            const int c = wid * 4 + j;           // 16 A chunk-blocks (8 rows each)
            load_lds16(Ag + kc + (size_t)c * 8 * 1024, &As[c * 512]);
        }
#pragma unroll
        for (int j = 0; j < 4; ++j) {
            const int c = wid * 4 + j;           // 16 B chunk-blocks
            load_lds16(Bg + kc + (size_t)c * 8 * 1024, &Bs[c * 512]);
        }
        __syncthreads();

#pragma unroll
        for (int ks = 0; ks < 2; ++ks) {
            const int ca = ((ks * 4 + quad) ^ (col & 7)) * 8;
            bf16x8 a[4], b[4];
#pragma unroll
            for (int i = 0; i < 4; ++i)
                a[i] = *reinterpret_cast<const bf16x8*>(
                    &As[(wm * 64 + i * 16 + col) * 64 + ca]);
#pragma unroll
            for (int i = 0; i < 4; ++i)
                b[i] = *reinterpret_cast<const bf16x8*>(
                    &Bs[(wn * 64 + i * 16 + col) * 64 + ca]);
#pragma unroll
            for (int mt = 0; mt < 4; ++mt)
#pragma unroll
                for (int nt = 0; nt < 4; ++nt)
                    acc[mt][nt] = MFMA16(a[mt], b[nt], acc[mt][nt]);
        }
    }

    const int w = blockIdx.x >> 3;   // 8 x-blocks per 1024 outputs: 0=Q 1=K 2=V
#pragma unroll
    for (int mt = 0; mt < 4; ++mt) {
#pragma unroll
        for (int nt = 0; nt < 4; ++nt) {
#pragma unroll
            for (int r = 0; r < 4; ++r) {
                int m = m0 + wm * 64 + mt * 16 + quad * 4 + r;
                int n = n0 + wn * 64 + nt * 16 + col;
                int bb = m >> 11, s = m & 2047;
                int n1 = n & 1023;
                int h = n1 >> 6, d = n1 & 63;
                size_t bh = (size_t)(bb * 16 + h);
                bf16 v = (bf16)acc[mt][nt][r];
                if (w == 0)      Qo[(bh * 2048 + s) * 64 + d] = v;
                else if (w == 1) Ko[(bh * 2048 + s) * 64 + d] = v;
                else             Vt[(bh * 64 + d) * 2048 + s] = v;
            }
        }
    }
}

// ---------------- V suffix tile sums (parallel) ----------------
__global__ __launch_bounds__(256) void tail_kernel(const bf16* __restrict__ Vt,
                                                   float* __restrict__ Tail) {
    const int bh = blockIdx.x;
    const bf16* Vg = Vt + (size_t)bh * 64 * 2048;
    float* Tg = Tail + (size_t)bh * 33 * 64;

    __shared__ float ts[64 * 33];
    const int tid = threadIdx.x;

#pragma unroll
    for (int i = 0; i < 8; ++i) {
        int task = i * 256 + tid;          // 0..2047
        int d = task >> 5, tt = task & 31;
        const bf16* p = &Vg[(size_t)d * 2048 + tt * 64];
        float s = 0.0f;
#pragma unroll
        for (int j = 0; j < 8; ++j) {
            bf16x8 v = *reinterpret_cast<const bf16x8*>(p + j * 8);
#pragma unroll
            for (int e = 0; e < 8; ++e) s += (float)v[e];
        }
        ts[d * 33 + tt] = s;
    }
    __syncthreads();

    if (tid < 64) {
        const int d = tid;
        float s = 0.0f;
        Tg[32 * 64 + d] = 0.0f;
        for (int tt = 31; tt >= 1; --tt) {
            s += ts[d * 33 + tt];
            Tg[tt * 64 + d] = s;
        }
    }
}

// ---------------- attention ----------------
// Paired q-tiles (qta, 31-qta): nta+ntb == 17 128-key chunks for every pair ->
// uniform work, 512 blocks = exactly 2/CU, all resident from t=0 (no tail).
// Both tiles consume the SAME staged K/V chunk; compute is merged so each
// kb/vb LDS read feeds TWO MFMAs on shared chunks. K/V double-buffered via
// register staging (no global_load_lds vmcnt drain): issue loads -> compute ->
// ds_write -> one barrier per 128 keys. Swapped QK^T (mfma(K,Q)): lane holds 4
// consecutive keys of one q-row -> P scatter is ds_write_b64. Q pre-scaled by
// log2(e)/32. Multiplicative mask: masked score=0 -> p=exp2(0)=1, still counted;
// fully-masked tail tiles handled via precomputed Tail suffix sums.
__global__ __launch_bounds__(256, 2) void attn_kernel(const bf16* __restrict__ Q,
                                                      const bf16* __restrict__ K,
                                                      const bf16* __restrict__ Vt,
                                                      const float* __restrict__ Tail,
                                                      float* __restrict__ out) {
    const int b   = blockIdx.z;
    const int h   = blockIdx.y;
    const int qta = blockIdx.x;          // 0..15  (light tile)
    const int qtb = 31 - qta;            // 16..31 (heavy tile)
    const int nta = (qta >> 1) + 1;      // 1..8   128-key chunks for tile a
    const int ntb = (qtb >> 1) + 1;      // 9..16  chunks for tile b (nta < ntb)

    const int t    = threadIdx.x;
    const int lane = t & 63;
    const int wid  = t >> 6;
    const int quad = lane >> 4;
    const int col  = lane & 15;

    const int bh = b * 16 + h;
    const bf16* Qg = Q + (size_t)bh * 2048 * 64;
    const bf16* Kg = K + (size_t)bh * 2048 * 64;
    const bf16* Vg = Vt + (size_t)bh * 64 * 2048;

    __shared__ __align__(16) bf16 Ks[2][128 * 64];   // 2 x 16 KB [key][d] swizzled
    __shared__ __align__(16) bf16 Vs[2][64 * 128];   // 2 x 16 KB [d][key] swizzled
    __shared__ __align__(16) bf16 Ps[2 * 4 * 16 * 36]; // 9 KB: per-tile per-wave P (32 keys)
    bf16* Pwb = &Ps[wid * 576];
    bf16* Pwa = &Ps[(4 + wid) * 576];

    const int q0a = qta * 64, q0b = qtb * 64;
    bf16x8 qfa[2], qfb[2];
#pragma unroll
    for (int ks = 0; ks < 2; ++ks) {
        qfa[ks] = *reinterpret_cast<const bf16x8*>(
            &Qg[(size_t)(q0a + wid * 16 + col) * 64 + ks * 32 + quad * 8]);
        qfb[ks] = *reinterpret_cast<const bf16x8*>(
            &Qg[(size_t)(q0b + wid * 16 + col) * 64 + ks * 32 + quad * 8]);
    }

    bf16x8 ones;
#pragma unroll
    for (int i = 0; i < 8; ++i) ones[i] = (bf16)1.0f;

    // init with fully-masked tail beyond 2*nt tiles (p == 1 there)
    f32x4 oa[4], ob[4], laa, lab;
    {
        const float tca = 64.0f * (float)(32 - 2 * nta);
        const float tcb = 64.0f * (float)(32 - 2 * ntb);
#pragma unroll
        for (int r = 0; r < 4; ++r) { laa[r] = tca; lab[r] = tcb; }
        const float* Tga = Tail + ((size_t)bh * 33 + 2 * nta) * 64;
        const float* Tgb = Tail + ((size_t)bh * 33 + 2 * ntb) * 64;
#pragma unroll
        for (int dt = 0; dt < 4; ++dt) {
            float tva = Tga[dt * 16 + col];
            float tvb = Tgb[dt * 16 + col];
#pragma unroll
            for (int r = 0; r < 4; ++r) { oa[dt][r] = tva; ob[dt][r] = tvb; }
        }
    }

    const int qcola = q0a + wid * 16 + col;   // q-index of this lane's sv cols
    const int qcolb = q0b + wid * 16 + col;
    const int qrowa = q0a + wid * 16 + quad * 4;  // output rows
    const int qrowb = q0b + wid * 16 + quad * 4;

    // staging task decomposition (4 tasks/thread each for K and V):
    // K: row = jj*32 + (t>>3), chunk = t&7;  V: d = jj*16 + (t>>4), chunk = t&15.
    // Global src pre-swizzled, LDS linear: LDS[r][c] = G[r][c ^ (r & mask)]
    const int rK   = t >> 3;
    const int cK   = t & 7;
    const int swzK = (cK ^ (rK & 7)) * 8;
    const int dV   = t >> 4;
    const int cV   = t & 15;
    const int swzV = (cV ^ dV) * 8;

    float4 kr[4], vr[4];

    // prologue: stage chunk 0 into buf 0
#pragma unroll
    for (int jj = 0; jj < 4; ++jj) {
        kr[jj] = *reinterpret_cast<const float4*>(
            &Kg[(size_t)(jj * 32 + rK) * 64 + swzK]);
        vr[jj] = *reinterpret_cast<const float4*>(
            &Vg[(size_t)(jj * 16 + dV) * 2048 + swzV]);
    }
#pragma unroll
    for (int jj = 0; jj < 4; ++jj) {
        *reinterpret_cast<float4*>(&Ks[0][(jj * 32 + rK) * 64 + cK * 8]) = kr[jj];
        *reinterpret_cast<float4*>(&Vs[0][(jj * 16 + dV) * 128 + cV * 8]) = vr[jj];
    }
    __syncthreads();

    for (int cc = 0; cc < ntb; ++cc) {
        const int  cur   = cc & 1;
        const bool acta  = (cc < nta);
        const bool diagb = (cc == ntb - 1);
        const bool diaga = (cc == nta - 1);
        const int  s0    = cc * 128;

        // issue next chunk's loads (in flight across all compute below)
        if (cc + 1 < ntb) {
            const int s0n = s0 + 128;
#pragma unroll
            for (int jj = 0; jj < 4; ++jj) {
                kr[jj] = *reinterpret_cast<const float4*>(
                    &Kg[(size_t)(s0n + jj * 32 + rK) * 64 + swzK]);
                vr[jj] = *reinterpret_cast<const float4*>(
                    &Vg[(size_t)(jj * 16 + dV) * 2048 + s0n + swzV]);
            }
        }

        const bf16* Kb_ = Ks[cur];
        const bf16* Vb_ = Vs[cur];

#pragma unroll
        for (int hh = 0; hh < 2; ++hh) {
            // QK^T for both tiles, sharing each kb read.
            // sv[n2][r] = S[key = s0 + hh*64 + n2*16 + quad*4 + r][q = qcol]
            f32x4 svb[4] = {}, sva[4] = {};
            __builtin_amdgcn_s_setprio(1);
#pragma unroll
            for (int ks = 0; ks < 2; ++ks) {
                const int ca = ((ks * 4 + quad) ^ (col & 7)) * 8;
#pragma unroll
                for (int n2 = 0; n2 < 4; ++n2) {
                    bf16x8 kb = *reinterpret_cast<const bf16x8*>(
                        &Kb_[((hh * 4 + n2) * 16 + col) * 64 + ca]);
                    svb[n2] = MFMA16(kb, qfb[ks], svb[n2]);
                    if (acta) sva[n2] = MFMA16(kb, qfa[ks], sva[n2]);
                }
            }
            __builtin_amdgcn_s_setprio(0);

            // multiplicative mask on the diagonal chunk of each tile
            if (diagb) {
#pragma unroll
                for (int n2 = 0; n2 < 4; ++n2)
#pragma unroll
                    for (int r = 0; r < 4; ++r) {
                        int kidx = s0 + hh * 64 + n2 * 16 + quad * 4 + r;
                        if (kidx > qcolb) svb[n2][r] = 0.0f;
                    }
            }
            if (acta && diaga) {
#pragma unroll
                for (int n2 = 0; n2 < 4; ++n2)
#pragma unroll
                    for (int r = 0; r < 4; ++r) {
                        int kidx = s0 + hh * 64 + n2 * 16 + quad * 4 + r;
                        if (kidx > qcola) sva[n2][r] = 0.0f;
                    }
            }

            // PV per 32-key group: write P (both tiles), read pa, share vb reads
#pragma unroll
            for (int gg = 0; gg < 2; ++gg) {
#pragma unroll
                for (int n22 = 0; n22 < 2; ++n22) {
                    const int n2 = gg * 2 + n22;
                    bf16x4 pw;
#pragma unroll
                    for (int r = 0; r < 4; ++r)
                        pw[r] = (bf16)__builtin_amdgcn_exp2f(svb[n2][r]);
                    *reinterpret_cast<bf16x4*>(
                        &Pwb[col * 36 + n22 * 16 + quad * 4]) = pw;
                    if (acta) {
                        bf16x4 pw2;
#pragma unroll
                        for (int r = 0; r < 4; ++r)
                            pw2[r] = (bf16)__builtin_amdgcn_exp2f(sva[n2][r]);
                        *reinterpret_cast<bf16x4*>(
                            &Pwa[col * 36 + n22 * 16 + quad * 4]) = pw2;
                    }
                }
                bf16x8 pab = *reinterpret_cast<const bf16x8*>(
                    &Pwb[col * 36 + quad * 8]);
                bf16x8 paa;
                if (acta) paa = *reinterpret_cast<const bf16x8*>(
                    &Pwa[col * 36 + quad * 8]);
                __builtin_amdgcn_s_setprio(1);
                lab = MFMA16(pab, ones, lab);
                if (acta) laa = MFMA16(paa, ones, laa);
#pragma unroll
                for (int dt = 0; dt < 4; ++dt) {
                    bf16x8 vb = *reinterpret_cast<const bf16x8*>(
                        &Vb_[(dt * 16 + col) * 128 +
                             (((hh * 2 + gg) * 4 + quad) ^ col) * 8]);
                    ob[dt] = MFMA16(pab, vb, ob[dt]);
                    if (acta) oa[dt] = MFMA16(paa, vb, oa[dt]);
                }
                __builtin_amdgcn_s_setprio(0);
            }
        }

        // commit prefetched regs into the other buffer (vmcnt wait lands here)
        if (cc + 1 < ntb) {
#pragma unroll
            for (int jj = 0; jj < 4; ++jj) {
                *reinterpret_cast<float4*>(
                    &Ks[cur ^ 1][(jj * 32 + rK) * 64 + cK * 8]) = kr[jj];
                *reinterpret_cast<float4*>(
                    &Vs[cur ^ 1][(jj * 16 + dV) * 128 + cV * 8]) = vr[jj];
            }
        }
        __syncthreads();
    }

#pragma unroll
    for (int r = 0; r < 4; ++r) {
        float inva = __builtin_amdgcn_rcpf(laa[r]);
        float invb = __builtin_amdgcn_rcpf(lab[r]);
#pragma unroll
        for (int dt = 0; dt < 4; ++dt) {
            int d = dt * 16 + col;
            out[((size_t)b * 2048 + qrowa + r) * 1024 + h * 64 + d] = oa[dt][r] * inva;
            out[((size_t)b * 2048 + qrowb + r) * 1024 + h * 64 + d] = ob[dt][r] * invb;
        }
    }
}

extern "C" void kernel_launch(void* const* d_in, const int* in_sizes, int n_in,
                              void* d_out, int out_size, void* d_ws, size_t ws_size,
                              hipStream_t stream) {
    const float* x  = (const float*)d_in[0];
    const float* Wq = (const float*)d_in[1];
    const float* Wk = (const float*)d_in[2];
    const float* Wv = (const float*)d_in[3];
    float* out = (float*)d_out;

    char* ws = (char*)d_ws;
    bf16*  xb   = (bf16*)(ws);                        // 8 MB
    bf16*  wb   = (bf16*)(ws + (size_t)(8  << 20));   // 6 MB [Wq|Wk|Wv]
    bf16*  Qb   = (bf16*)(ws + (size_t)(14 << 20));   // 8 MB [B,H,S,D] (pre-scaled)
    bf16*  Kb   = (bf16*)(ws + (size_t)(22 << 20));   // 8 MB [B,H,S,D]
    bf16*  Vtb  = (bf16*)(ws + (size_t)(30 << 20));   // 8 MB [B,H,D,S]
    float* Tail = (float*)(ws + (size_t)(38 << 20));  // 264 KB

    const float QSCALE = 1.44269504088896f / 32.0f;   // log2(e)/sqrt(E)

    cast_all<<<7168, 256, 0, stream>>>(x, Wq, Wk, Wv, xb, wb, QSCALE);

    qkv_gemm<<<dim3(24, 32), 256, 0, stream>>>(xb, wb, Qb, Kb, Vtb);

    tail_kernel<<<32, 256, 0, stream>>>(Vtb, Tail);

    attn_kernel<<<dim3(16, 16, 2), 256, 0, stream>>>(Qb, Kb, Vtb, Tail, out);
}

// Round 5
// 183.778 us; speedup vs baseline: 1.2867x; 1.2867x over previous
//
#include <hip/hip_runtime.h>
#include <hip/hip_bf16.h>
#include <cstdint>

using bf16   = __bf16;
using bf16x4 = __attribute__((ext_vector_type(4))) __bf16;
using bf16x8 = __attribute__((ext_vector_type(8))) __bf16;
using f32x4  = __attribute__((ext_vector_type(4))) float;

#define MFMA16(a, b, c) __builtin_amdgcn_mfma_f32_16x16x32_bf16((a), (b), (c), 0, 0, 0)

// async global->LDS, 16B per lane; LDS dest = wave-uniform base + lane*16.
__device__ __forceinline__ void load_lds16(const bf16* g, bf16* l) {
    __builtin_amdgcn_global_load_lds(
        (const __attribute__((address_space(1))) void*)g,
        (__attribute__((address_space(3))) void*)l, 16, 0, 0);
}

// ---------------- fused cast fp32 -> bf16 (x, Wq*scale, Wk, Wv) ----------------
__global__ __launch_bounds__(256) void cast_all(const float* __restrict__ x,
                                                const float* __restrict__ Wq,
                                                const float* __restrict__ Wk,
                                                const float* __restrict__ Wv,
                                                bf16* __restrict__ xb,
                                                bf16* __restrict__ wb,
                                                float qscale) {
    int i = blockIdx.x * 256 + threadIdx.x;   // float4 index, 1835008 total
    const float* src; bf16* dst; int off; float scale = 1.0f;
    if (i < 1048576)      { src = x;  dst = xb;              off = i; }
    else if (i < 1310720) { src = Wq; dst = wb;              off = i - 1048576; scale = qscale; }
    else if (i < 1572864) { src = Wk; dst = wb + (1u << 20); off = i - 1310720; }
    else                  { src = Wv; dst = wb + (2u << 20); off = i - 1572864; }
    float4 v = reinterpret_cast<const float4*>(src)[off];
    bf16x4 o;
    o[0] = (bf16)(v.x * scale); o[1] = (bf16)(v.y * scale);
    o[2] = (bf16)(v.z * scale); o[3] = (bf16)(v.w * scale);
    reinterpret_cast<bf16x4*>(dst)[off] = o;
}

// ---------------- fused QKV projection: y = x @ [Wq|Wk|Wv]^T ----------------
// 128x128 tiles (m97 structure), BK=64 -> 768 blocks = 3/CU, acc 4x4 per wave.
// CONFIRMED ~17.5 us faster than the 128x64 version (R2->R3 delta attribution).
// LDS[row][cc] = global[row][cc ^ (row&7)] (8-elem chunks, conflict-free readback)
__global__ __launch_bounds__(256) void qkv_gemm(const bf16* __restrict__ xb,
                                                const bf16* __restrict__ wb,
                                                bf16* __restrict__ Qo,
                                                bf16* __restrict__ Ko,
                                                bf16* __restrict__ Vt) {
    const int n0 = blockIdx.x * 128;
    const int m0 = blockIdx.y * 128;

    __shared__ __align__(16) bf16 As[128 * 64];   // 16 KB
    __shared__ __align__(16) bf16 Bs[128 * 64];   // 16 KB

    const int t    = threadIdx.x;
    const int lane = t & 63;
    const int wid  = t >> 6;
    const int quad = lane >> 4;
    const int col  = lane & 15;
    const int wm   = wid & 1;      // M half (64)
    const int wn   = wid >> 1;     // N half (64)

    const int rsub = lane >> 3;
    const int csw  = ((lane & 7) ^ rsub) * 8;

    f32x4 acc[4][4] = {};

    const bf16* Ag = &xb[(size_t)(m0 + rsub) * 1024 + csw];
    const bf16* Bg = &wb[(size_t)(n0 + rsub) * 1024 + csw];

    for (int kc = 0; kc < 1024; kc += 64) {
        __syncthreads();
#pragma unroll
        for (int j = 0; j < 4; ++j) {
            const int c = wid * 4 + j;           // 16 A chunk-blocks (8 rows each)
            load_lds16(Ag + kc + (size_t)c * 8 * 1024, &As[c * 512]);
        }
#pragma unroll
        for (int j = 0; j < 4; ++j) {
            const int c = wid * 4 + j;           // 16 B chunk-blocks
            load_lds16(Bg + kc + (size_t)c * 8 * 1024, &Bs[c * 512]);
        }
        __syncthreads();

#pragma unroll
        for (int ks = 0; ks < 2; ++ks) {
            const int ca = ((ks * 4 + quad) ^ (col & 7)) * 8;
            bf16x8 a[4], b[4];
#pragma unroll
            for (int i = 0; i < 4; ++i)
                a[i] = *reinterpret_cast<const bf16x8*>(
                    &As[(wm * 64 + i * 16 + col) * 64 + ca]);
#pragma unroll
            for (int i = 0; i < 4; ++i)
                b[i] = *reinterpret_cast<const bf16x8*>(
                    &Bs[(wn * 64 + i * 16 + col) * 64 + ca]);
#pragma unroll
            for (int mt = 0; mt < 4; ++mt)
#pragma unroll
                for (int nt = 0; nt < 4; ++nt)
                    acc[mt][nt] = MFMA16(a[mt], b[nt], acc[mt][nt]);
        }
    }

    const int w = blockIdx.x >> 3;   // 8 x-blocks per 1024 outputs: 0=Q 1=K 2=V
#pragma unroll
    for (int mt = 0; mt < 4; ++mt) {
#pragma unroll
        for (int nt = 0; nt < 4; ++nt) {
#pragma unroll
            for (int r = 0; r < 4; ++r) {
                int m = m0 + wm * 64 + mt * 16 + quad * 4 + r;
                int n = n0 + wn * 64 + nt * 16 + col;
                int bb = m >> 11, s = m & 2047;
                int n1 = n & 1023;
                int h = n1 >> 6, d = n1 & 63;
                size_t bh = (size_t)(bb * 16 + h);
                bf16 v = (bf16)acc[mt][nt][r];
                if (w == 0)      Qo[(bh * 2048 + s) * 64 + d] = v;
                else if (w == 1) Ko[(bh * 2048 + s) * 64 + d] = v;
                else             Vt[(bh * 64 + d) * 2048 + s] = v;
            }
        }
    }
}

// ---------------- V suffix tile sums (parallel) ----------------
__global__ __launch_bounds__(256) void tail_kernel(const bf16* __restrict__ Vt,
                                                   float* __restrict__ Tail) {
    const int bh = blockIdx.x;
    const bf16* Vg = Vt + (size_t)bh * 64 * 2048;
    float* Tg = Tail + (size_t)bh * 33 * 64;

    __shared__ float ts[64 * 33];
    const int tid = threadIdx.x;

#pragma unroll
    for (int i = 0; i < 8; ++i) {
        int task = i * 256 + tid;          // 0..2047
        int d = task >> 5, tt = task & 31;
        const bf16* p = &Vg[(size_t)d * 2048 + tt * 64];
        float s = 0.0f;
#pragma unroll
        for (int j = 0; j < 8; ++j) {
            bf16x8 v = *reinterpret_cast<const bf16x8*>(p + j * 8);
#pragma unroll
            for (int e = 0; e < 8; ++e) s += (float)v[e];
        }
        ts[d * 33 + tt] = s;
    }
    __syncthreads();

    if (tid < 64) {
        const int d = tid;
        float s = 0.0f;
        Tg[32 * 64 + d] = 0.0f;
        for (int tt = 31; tt >= 1; --tt) {
            s += ts[d * 33 + tt];
            Tg[tt * 64 + d] = s;
        }
    }
}

// ---------------- attention ----------------
// R0 structure (best measured: 52.6 us): 128-key chunks, global_load_lds
// staging, 41 KB LDS -> 3 blocks/CU. Q pre-scaled by log2(e)/32.
// Multiplicative mask: masked score=0 -> p=exp2(0)=1, still counted — fully-
// masked tail tiles handled via precomputed Tail suffix sums.
__global__ __launch_bounds__(256) void attn_kernel(const bf16* __restrict__ Q,
                                                   const bf16* __restrict__ K,
                                                   const bf16* __restrict__ Vt,
                                                   const float* __restrict__ Tail,
                                                   float* __restrict__ out) {
    const int b = blockIdx.z;
    const int h = blockIdx.y;
    const int j  = ((blockIdx.y >> 3) ^ blockIdx.z) & 1;
    const int qt = j ? (31 - (int)blockIdx.x) : (int)blockIdx.x;
    const int q0 = qt * 64;
    const int np = (qt >> 1) + 1;          // 128-key pairs to process in-loop

    const int t    = threadIdx.x;
    const int lane = t & 63;
    const int wid  = t >> 6;
    const int quad = lane >> 4;
    const int col  = lane & 15;

    const int bh = b * 16 + h;
    const bf16* Qg = Q + (size_t)bh * 2048 * 64;
    const bf16* Kg = K + (size_t)bh * 2048 * 64;
    const bf16* Vg = Vt + (size_t)bh * 64 * 2048;

    __shared__ __align__(16) bf16 Ks[128 * 64];     // 16 KB: [key][d], swizzled
    __shared__ __align__(16) bf16 Vs[64 * 128];     // 16 KB: [d][key], swizzled
    __shared__ __align__(16) bf16 Ps[4 * 16 * 72];  // wave-private P
    bf16* Pw = &Ps[wid * 16 * 72];

    bf16x8 qf[2];
#pragma unroll
    for (int ks = 0; ks < 2; ++ks)
        qf[ks] = *reinterpret_cast<const bf16x8*>(
            &Qg[(size_t)(q0 + wid * 16 + col) * 64 + ks * 32 + quad * 8]);

    bf16x8 ones;
#pragma unroll
    for (int i = 0; i < 8; ++i) ones[i] = (bf16)1.0f;

    // init with fully-masked tail beyond 2*np tiles (p == 1 there)
    f32x4 o[4];
    f32x4 la;
    {
        const float tc = 64.0f * (float)(32 - 2 * np);
#pragma unroll
        for (int r = 0; r < 4; ++r) la[r] = tc;
        const float* Tg = Tail + ((size_t)bh * 33 + 2 * np) * 64;
#pragma unroll
        for (int dt = 0; dt < 4; ++dt) {
            float tv = Tg[dt * 16 + col];
#pragma unroll
            for (int r = 0; r < 4; ++r) o[dt][r] = tv;
        }
    }

    const int qrow = q0 + wid * 16 + quad * 4;
    // K staging: 16 chunk-blocks of 8 rows x 64; V staging: 16 chunk-blocks of 4 rows x 128
    const int rsubK = lane >> 3;
    const int cswK  = ((lane & 7) ^ rsubK) * 8;
    const int rV    = lane >> 4;
    const int ccV   = lane & 15;

    const int s0max = (np - 1) * 128;

    for (int s0 = 0; s0 < np * 128; s0 += 128) {
        __syncthreads();
#pragma unroll
        for (int jj = 0; jj < 4; ++jj) {
            const int c = wid * 4 + jj;
            load_lds16(&Kg[(size_t)(s0 + c * 8 + rsubK) * 64 + cswK], &Ks[c * 512]);
            const int d = c * 4 + rV;
            load_lds16(&Vg[(size_t)d * 2048 + s0 + ((ccV ^ (d & 15)) * 8)], &Vs[c * 512]);
        }
        __syncthreads();

        // S' = (Q*log2e/32) K^T over 8 key-subtiles
        f32x4 sv[8] = {};
#pragma unroll
        for (int ks = 0; ks < 2; ++ks) {
            const int ca = ((ks * 4 + quad) ^ (col & 7)) * 8;
#pragma unroll
            for (int nt = 0; nt < 8; ++nt) {
                bf16x8 kb = *reinterpret_cast<const bf16x8*>(
                    &Ks[(nt * 16 + col) * 64 + ca]);
                sv[nt] = MFMA16(qf[ks], kb, sv[nt]);
            }
        }

        // multiplicative mask only on the last pair (covers diagonal + dead upper half)
        if (s0 == s0max) {
#pragma unroll
            for (int nt = 0; nt < 8; ++nt) {
                int kidx = s0 + nt * 16 + col;
#pragma unroll
                for (int r = 0; r < 4; ++r)
                    if (kidx > qrow + r) sv[nt][r] = 0.0f;
            }
        }

        // PV in two 64-key halves, reusing wave-private Ps
#pragma unroll
        for (int hh = 0; hh < 2; ++hh) {
#pragma unroll
            for (int nt = 0; nt < 4; ++nt)
#pragma unroll
                for (int r = 0; r < 4; ++r)
                    Pw[(quad * 4 + r) * 72 + nt * 16 + col] =
                        (bf16)__builtin_amdgcn_exp2f(sv[hh * 4 + nt][r]);

#pragma unroll
            for (int gg = 0; gg < 2; ++gg) {
                bf16x8 pa = *reinterpret_cast<const bf16x8*>(
                    &Pw[col * 72 + gg * 32 + quad * 8]);
                la = MFMA16(pa, ones, la);
                const int g = hh * 2 + gg;
#pragma unroll
                for (int dt = 0; dt < 4; ++dt) {
                    bf16x8 vb = *reinterpret_cast<const bf16x8*>(
                        &Vs[(dt * 16 + col) * 128 + ((g * 4 + quad) ^ col) * 8]);
                    o[dt] = MFMA16(pa, vb, o[dt]);
                }
            }
        }
    }

#pragma unroll
    for (int r = 0; r < 4; ++r) {
        int q = qrow + r;
        float inv = __builtin_amdgcn_rcpf(la[r]);
#pragma unroll
        for (int dt = 0; dt < 4; ++dt) {
            int d = dt * 16 + col;
            out[((size_t)b * 2048 + q) * 1024 + h * 64 + d] = o[dt][r] * inv;
        }
    }
}

extern "C" void kernel_launch(void* const* d_in, const int* in_sizes, int n_in,
                              void* d_out, int out_size, void* d_ws, size_t ws_size,
                              hipStream_t stream) {
    const float* x  = (const float*)d_in[0];
    const float* Wq = (const float*)d_in[1];
    const float* Wk = (const float*)d_in[2];
    const float* Wv = (const float*)d_in[3];
    float* out = (float*)d_out;

    char* ws = (char*)d_ws;
    bf16*  xb   = (bf16*)(ws);                        // 8 MB
    bf16*  wb   = (bf16*)(ws + (size_t)(8  << 20));   // 6 MB [Wq|Wk|Wv]
    bf16*  Qb   = (bf16*)(ws + (size_t)(14 << 20));   // 8 MB [B,H,S,D] (pre-scaled)
    bf16*  Kb   = (bf16*)(ws + (size_t)(22 << 20));   // 8 MB [B,H,S,D]
    bf16*  Vtb  = (bf16*)(ws + (size_t)(30 << 20));   // 8 MB [B,H,D,S]
    float* Tail = (float*)(ws + (size_t)(38 << 20));  // 264 KB

    const float QSCALE = 1.44269504088896f / 32.0f;   // log2(e)/sqrt(E)

    cast_all<<<7168, 256, 0, stream>>>(x, Wq, Wk, Wv, xb, wb, QSCALE);

    qkv_gemm<<<dim3(24, 32), 256, 0, stream>>>(xb, wb, Qb, Kb, Vtb);

    tail_kernel<<<32, 256, 0, stream>>>(Vtb, Tail);

    attn_kernel<<<dim3(32, 16, 2), 256, 0, stream>>>(Qb, Kb, Vtb, Tail, out);
}

// Round 6
// 177.116 us; speedup vs baseline: 1.3351x; 1.0376x over previous
//
#include <hip/hip_runtime.h>
#include <hip/hip_bf16.h>
#include <cstdint>

using bf16   = __bf16;
using bf16x4 = __attribute__((ext_vector_type(4))) __bf16;
using bf16x8 = __attribute__((ext_vector_type(8))) __bf16;
using f32x4  = __attribute__((ext_vector_type(4))) float;

#define MFMA16(a, b, c) __builtin_amdgcn_mfma_f32_16x16x32_bf16((a), (b), (c), 0, 0, 0)

// async global->LDS, 16B per lane; LDS dest = wave-uniform base + lane*16.
__device__ __forceinline__ void load_lds16(const bf16* g, bf16* l) {
    __builtin_amdgcn_global_load_lds(
        (const __attribute__((address_space(1))) void*)g,
        (__attribute__((address_space(3))) void*)l, 16, 0, 0);
}

// ---------------- fused cast fp32 -> bf16 (x, Wq*scale, Wk, Wv) ----------------
__global__ __launch_bounds__(256) void cast_all(const float* __restrict__ x,
                                                const float* __restrict__ Wq,
                                                const float* __restrict__ Wk,
                                                const float* __restrict__ Wv,
                                                bf16* __restrict__ xb,
                                                bf16* __restrict__ wb,
                                                float qscale) {
    int i = blockIdx.x * 256 + threadIdx.x;   // float4 index, 1835008 total
    const float* src; bf16* dst; int off; float scale = 1.0f;
    if (i < 1048576)      { src = x;  dst = xb;              off = i; }
    else if (i < 1310720) { src = Wq; dst = wb;              off = i - 1048576; scale = qscale; }
    else if (i < 1572864) { src = Wk; dst = wb + (1u << 20); off = i - 1310720; }
    else                  { src = Wv; dst = wb + (2u << 20); off = i - 1572864; }
    float4 v = reinterpret_cast<const float4*>(src)[off];
    bf16x4 o;
    o[0] = (bf16)(v.x * scale); o[1] = (bf16)(v.y * scale);
    o[2] = (bf16)(v.z * scale); o[3] = (bf16)(v.w * scale);
    reinterpret_cast<bf16x4*>(dst)[off] = o;
}

// ---------------- fused QKV projection: y = x @ [Wq|Wk|Wv]^T ----------------
// 128x128 tiles (m97 structure), BK=64 -> 768 blocks = 3/CU, acc 4x4 per wave.
// CONFIRMED win vs 128x64 (R3/R5 delta attribution, ~13 us).
// LDS[row][cc] = global[row][cc ^ (row&7)] (8-elem chunks, conflict-free readback)
__global__ __launch_bounds__(256) void qkv_gemm(const bf16* __restrict__ xb,
                                                const bf16* __restrict__ wb,
                                                bf16* __restrict__ Qo,
                                                bf16* __restrict__ Ko,
                                                bf16* __restrict__ Vt) {
    const int n0 = blockIdx.x * 128;
    const int m0 = blockIdx.y * 128;

    __shared__ __align__(16) bf16 As[128 * 64];   // 16 KB
    __shared__ __align__(16) bf16 Bs[128 * 64];   // 16 KB

    const int t    = threadIdx.x;
    const int lane = t & 63;
    const int wid  = t >> 6;
    const int quad = lane >> 4;
    const int col  = lane & 15;
    const int wm   = wid & 1;      // M half (64)
    const int wn   = wid >> 1;     // N half (64)

    const int rsub = lane >> 3;
    const int csw  = ((lane & 7) ^ rsub) * 8;

    f32x4 acc[4][4] = {};

    const bf16* Ag = &xb[(size_t)(m0 + rsub) * 1024 + csw];
    const bf16* Bg = &wb[(size_t)(n0 + rsub) * 1024 + csw];

    for (int kc = 0; kc < 1024; kc += 64) {
        __syncthreads();
#pragma unroll
        for (int j = 0; j < 4; ++j) {
            const int c = wid * 4 + j;           // 16 A chunk-blocks (8 rows each)
            load_lds16(Ag + kc + (size_t)c * 8 * 1024, &As[c * 512]);
        }
#pragma unroll
        for (int j = 0; j < 4; ++j) {
            const int c = wid * 4 + j;           // 16 B chunk-blocks
            load_lds16(Bg + kc + (size_t)c * 8 * 1024, &Bs[c * 512]);
        }
        __syncthreads();

#pragma unroll
        for (int ks = 0; ks < 2; ++ks) {
            const int ca = ((ks * 4 + quad) ^ (col & 7)) * 8;
            bf16x8 a[4], b[4];
#pragma unroll
            for (int i = 0; i < 4; ++i)
                a[i] = *reinterpret_cast<const bf16x8*>(
                    &As[(wm * 64 + i * 16 + col) * 64 + ca]);
#pragma unroll
            for (int i = 0; i < 4; ++i)
                b[i] = *reinterpret_cast<const bf16x8*>(
                    &Bs[(wn * 64 + i * 16 + col) * 64 + ca]);
#pragma unroll
            for (int mt = 0; mt < 4; ++mt)
#pragma unroll
                for (int nt = 0; nt < 4; ++nt)
                    acc[mt][nt] = MFMA16(a[mt], b[nt], acc[mt][nt]);
        }
    }

    const int w = blockIdx.x >> 3;   // 8 x-blocks per 1024 outputs: 0=Q 1=K 2=V
#pragma unroll
    for (int mt = 0; mt < 4; ++mt) {
#pragma unroll
        for (int nt = 0; nt < 4; ++nt) {
#pragma unroll
            for (int r = 0; r < 4; ++r) {
                int m = m0 + wm * 64 + mt * 16 + quad * 4 + r;
                int n = n0 + wn * 64 + nt * 16 + col;
                int bb = m >> 11, s = m & 2047;
                int n1 = n & 1023;
                int h = n1 >> 6, d = n1 & 63;
                size_t bh = (size_t)(bb * 16 + h);
                bf16 v = (bf16)acc[mt][nt][r];
                if (w == 0)      Qo[(bh * 2048 + s) * 64 + d] = v;
                else if (w == 1) Ko[(bh * 2048 + s) * 64 + d] = v;
                else             Vt[(bh * 64 + d) * 2048 + s] = v;
            }
        }
    }
}

// ---------------- V suffix tile sums (parallel) ----------------
__global__ __launch_bounds__(256) void tail_kernel(const bf16* __restrict__ Vt,
                                                   float* __restrict__ Tail) {
    const int bh = blockIdx.x;
    const bf16* Vg = Vt + (size_t)bh * 64 * 2048;
    float* Tg = Tail + (size_t)bh * 33 * 64;

    __shared__ float ts[64 * 33];
    const int tid = threadIdx.x;

#pragma unroll
    for (int i = 0; i < 8; ++i) {
        int task = i * 256 + tid;          // 0..2047
        int d = task >> 5, tt = task & 31;
        const bf16* p = &Vg[(size_t)d * 2048 + tt * 64];
        float s = 0.0f;
#pragma unroll
        for (int j = 0; j < 8; ++j) {
            bf16x8 v = *reinterpret_cast<const bf16x8*>(p + j * 8);
#pragma unroll
            for (int e = 0; e < 8; ++e) s += (float)v[e];
        }
        ts[d * 33 + tt] = s;
    }
    __syncthreads();

    if (tid < 64) {
        const int d = tid;
        float s = 0.0f;
        Tg[32 * 64 + d] = 0.0f;
        for (int tt = 31; tt >= 1; --tt) {
            s += ts[d * 33 + tt];
            Tg[tt * 64 + d] = s;
        }
    }
}

// ---------------- attention ----------------
// R0 geometry (128-key chunks, global_load_lds staging, 3 blocks/CU) with
// 2-way LDS-operand reuse via wave reassignment:
//   QK phase: wave (qh=wid&1, kh=wid>>1) computes S for q[qh*32..+32) x
//   keys[kh*64..+64) with SWAPPED mfma(K,Q) (R2-verified): each kb read feeds
//   2 MFMAs, P scatter is ds_write_b64 (8/wave vs 32 scalar b16).
//   P is block-shared [64 q][136 key] (+1 barrier).
//   PV phase: wave (qh, dh=wid>>1) computes o for q[qh*32..+32) x d[dh*32..+32)
//   over all 128 keys: each vb read feeds 2 MFMAs.
// b128 reads/wave/chunk: 36 -> 24. Q pre-scaled by log2(e)/32. Multiplicative
// mask: masked score=0 -> p=exp2(0)=1, still counted; fully-masked tail tiles
// handled via precomputed Tail suffix sums.
__global__ __launch_bounds__(256) void attn_kernel(const bf16* __restrict__ Q,
                                                   const bf16* __restrict__ K,
                                                   const bf16* __restrict__ Vt,
                                                   const float* __restrict__ Tail,
                                                   float* __restrict__ out) {
    const int b = blockIdx.z;
    const int h = blockIdx.y;
    const int j  = ((blockIdx.y >> 3) ^ blockIdx.z) & 1;
    const int qt = j ? (31 - (int)blockIdx.x) : (int)blockIdx.x;
    const int q0 = qt * 64;
    const int np = (qt >> 1) + 1;          // 128-key chunks to process in-loop

    const int t    = threadIdx.x;
    const int lane = t & 63;
    const int wid  = t >> 6;
    const int quad = lane >> 4;
    const int col  = lane & 15;
    const int qh   = wid & 1;     // q-half (32 rows) for both phases
    const int kh   = wid >> 1;    // key-half (QK) / d-half (PV)

    const int bh = b * 16 + h;
    const bf16* Qg = Q + (size_t)bh * 2048 * 64;
    const bf16* Kg = K + (size_t)bh * 2048 * 64;
    const bf16* Vg = Vt + (size_t)bh * 64 * 2048;

    __shared__ __align__(16) bf16 Ks[128 * 64];   // 16 KB: [key][d], swizzled
    __shared__ __align__(16) bf16 Vs[64 * 128];   // 16 KB: [d][key], swizzled
    __shared__ __align__(16) bf16 Ps[64 * 136];   // 17 KB: [q][key], shared

    // Q frags: qf[qs][ks] for the wave's 2 q-subtiles
    bf16x8 qf[2][2];
#pragma unroll
    for (int qs = 0; qs < 2; ++qs)
#pragma unroll
        for (int ks = 0; ks < 2; ++ks)
            qf[qs][ks] = *reinterpret_cast<const bf16x8*>(
                &Qg[(size_t)(q0 + qh * 32 + qs * 16 + col) * 64 + ks * 32 + quad * 8]);

    bf16x8 ones;
#pragma unroll
    for (int i = 0; i < 8; ++i) ones[i] = (bf16)1.0f;

    // init with fully-masked tail beyond 2*np tiles (p == 1 there)
    f32x4 o[2][2];
    f32x4 la[2];
    {
        const float tc = 64.0f * (float)(32 - 2 * np);
#pragma unroll
        for (int qs = 0; qs < 2; ++qs)
#pragma unroll
            for (int r = 0; r < 4; ++r) la[qs][r] = tc;
        const float* Tg = Tail + ((size_t)bh * 33 + 2 * np) * 64;
#pragma unroll
        for (int dt = 0; dt < 2; ++dt) {
            float tv = Tg[kh * 32 + dt * 16 + col];
#pragma unroll
            for (int qs = 0; qs < 2; ++qs)
#pragma unroll
                for (int r = 0; r < 4; ++r) o[qs][dt][r] = tv;
        }
    }

    // K staging: 16 chunk-blocks of 8 rows x 64; V staging: 16 chunk-blocks of 4 rows x 128
    const int rsubK = lane >> 3;
    const int cswK  = ((lane & 7) ^ rsubK) * 8;
    const int rV    = lane >> 4;
    const int ccV   = lane & 15;

    const int s0max = (np - 1) * 128;

    for (int s0 = 0; s0 < np * 128; s0 += 128) {
        __syncthreads();
#pragma unroll
        for (int jj = 0; jj < 4; ++jj) {
            const int c = wid * 4 + jj;
            load_lds16(&Kg[(size_t)(s0 + c * 8 + rsubK) * 64 + cswK], &Ks[c * 512]);
            const int d = c * 4 + rV;
            load_lds16(&Vg[(size_t)d * 2048 + s0 + ((ccV ^ (d & 15)) * 8)], &Vs[c * 512]);
        }
        __syncthreads();

        // QK (swapped): S^T for keys [kh*64..+64) x q [qh*32..+32)
        // sv[qs][nt][r] = S[key = s0+kh*64+nt*16+quad*4+r][q = q0+qh*32+qs*16+col]
        f32x4 sv[2][4] = {};
        __builtin_amdgcn_s_setprio(1);
#pragma unroll
        for (int ks = 0; ks < 2; ++ks) {
            const int ca = ((ks * 4 + quad) ^ (col & 7)) * 8;
#pragma unroll
            for (int nt = 0; nt < 4; ++nt) {
                bf16x8 kb = *reinterpret_cast<const bf16x8*>(
                    &Ks[((kh * 4 + nt) * 16 + col) * 64 + ca]);
                sv[0][nt] = MFMA16(kb, qf[0][ks], sv[0][nt]);
                sv[1][nt] = MFMA16(kb, qf[1][ks], sv[1][nt]);
            }
        }
        __builtin_amdgcn_s_setprio(0);

        // multiplicative mask only on the last chunk (covers diagonal + dead upper)
        if (s0 == s0max) {
#pragma unroll
            for (int qs = 0; qs < 2; ++qs) {
                const int qc = q0 + qh * 32 + qs * 16 + col;
#pragma unroll
                for (int nt = 0; nt < 4; ++nt)
#pragma unroll
                    for (int r = 0; r < 4; ++r) {
                        int kidx = s0 + kh * 64 + nt * 16 + quad * 4 + r;
                        if (kidx > qc) sv[qs][nt][r] = 0.0f;
                    }
            }
        }

        // exp2 + pack 4 consecutive keys -> ds_write_b64 into shared P [q][key]
#pragma unroll
        for (int qs = 0; qs < 2; ++qs) {
            bf16* Pq = &Ps[(qh * 32 + qs * 16 + col) * 136 + kh * 64];
#pragma unroll
            for (int nt = 0; nt < 4; ++nt) {
                bf16x4 pw;
#pragma unroll
                for (int r = 0; r < 4; ++r)
                    pw[r] = (bf16)__builtin_amdgcn_exp2f(sv[qs][nt][r]);
                *reinterpret_cast<bf16x4*>(&Pq[nt * 16 + quad * 4]) = pw;
            }
        }

        __syncthreads();   // P quadrants from all waves visible

        // PV: o[q-half qh][d-half kh] over all 128 keys; vb shared by 2 q-subs
        __builtin_amdgcn_s_setprio(1);
#pragma unroll
        for (int kg = 0; kg < 4; ++kg) {
            bf16x8 pa0 = *reinterpret_cast<const bf16x8*>(
                &Ps[(qh * 32 + col) * 136 + kg * 32 + quad * 8]);
            bf16x8 pa1 = *reinterpret_cast<const bf16x8*>(
                &Ps[(qh * 32 + 16 + col) * 136 + kg * 32 + quad * 8]);
            la[0] = MFMA16(pa0, ones, la[0]);
            la[1] = MFMA16(pa1, ones, la[1]);
#pragma unroll
            for (int dt = 0; dt < 2; ++dt) {
                bf16x8 vb = *reinterpret_cast<const bf16x8*>(
                    &Vs[(kh * 32 + dt * 16 + col) * 128 + ((kg * 4 + quad) ^ col) * 8]);
                o[0][dt] = MFMA16(pa0, vb, o[0][dt]);
                o[1][dt] = MFMA16(pa1, vb, o[1][dt]);
            }
        }
        __builtin_amdgcn_s_setprio(0);
    }

#pragma unroll
    for (int qs = 0; qs < 2; ++qs) {
#pragma unroll
        for (int r = 0; r < 4; ++r) {
            int q = q0 + qh * 32 + qs * 16 + quad * 4 + r;
            float inv = __builtin_amdgcn_rcpf(la[qs][r]);
#pragma unroll
            for (int dt = 0; dt < 2; ++dt) {
                int d = kh * 32 + dt * 16 + col;
                out[((size_t)b * 2048 + q) * 1024 + h * 64 + d] = o[qs][dt][r] * inv;
            }
        }
    }
}

extern "C" void kernel_launch(void* const* d_in, const int* in_sizes, int n_in,
                              void* d_out, int out_size, void* d_ws, size_t ws_size,
                              hipStream_t stream) {
    const float* x  = (const float*)d_in[0];
    const float* Wq = (const float*)d_in[1];
    const float* Wk = (const float*)d_in[2];
    const float* Wv = (const float*)d_in[3];
    float* out = (float*)d_out;

    char* ws = (char*)d_ws;
    bf16*  xb   = (bf16*)(ws);                        // 8 MB
    bf16*  wb   = (bf16*)(ws + (size_t)(8  << 20));   // 6 MB [Wq|Wk|Wv]
    bf16*  Qb   = (bf16*)(ws + (size_t)(14 << 20));   // 8 MB [B,H,S,D] (pre-scaled)
    bf16*  Kb   = (bf16*)(ws + (size_t)(22 << 20));   // 8 MB [B,H,S,D]
    bf16*  Vtb  = (bf16*)(ws + (size_t)(30 << 20));   // 8 MB [B,H,D,S]
    float* Tail = (float*)(ws + (size_t)(38 << 20));  // 264 KB

    const float QSCALE = 1.44269504088896f / 32.0f;   // log2(e)/sqrt(E)

    cast_all<<<7168, 256, 0, stream>>>(x, Wq, Wk, Wv, xb, wb, QSCALE);

    qkv_gemm<<<dim3(24, 32), 256, 0, stream>>>(xb, wb, Qb, Kb, Vtb);

    tail_kernel<<<32, 256, 0, stream>>>(Vtb, Tail);

    attn_kernel<<<dim3(32, 16, 2), 256, 0, stream>>>(Qb, Kb, Vtb, Tail, out);
}

// Round 8
// 174.212 us; speedup vs baseline: 1.3573x; 1.0167x over previous
//
#include <hip/hip_runtime.h>
#include <hip/hip_bf16.h>
#include <cstdint>

using bf16   = __bf16;
using bf16x4 = __attribute__((ext_vector_type(4))) __bf16;
using bf16x8 = __attribute__((ext_vector_type(8))) __bf16;
using f32x4  = __attribute__((ext_vector_type(4))) float;

#define MFMA16(a, b, c) __builtin_amdgcn_mfma_f32_16x16x32_bf16((a), (b), (c), 0, 0, 0)

// async global->LDS, 16B per lane; LDS dest = wave-uniform base + lane*16.
// CONTRACT (R7 lesson): staging must be bounded by __syncthreads on BOTH sides;
// overlapping single-buffered stages with compute races.
__device__ __forceinline__ void load_lds16(const bf16* g, bf16* l) {
    __builtin_amdgcn_global_load_lds(
        (const __attribute__((address_space(1))) void*)g,
        (__attribute__((address_space(3))) void*)l, 16, 0, 0);
}

// ---------------- fused cast fp32 -> bf16 (x, Wq*scale, Wk, Wv) ----------------
__global__ __launch_bounds__(256) void cast_all(const float* __restrict__ x,
                                                const float* __restrict__ Wq,
                                                const float* __restrict__ Wk,
                                                const float* __restrict__ Wv,
                                                bf16* __restrict__ xb,
                                                bf16* __restrict__ wb,
                                                float qscale) {
    int i = blockIdx.x * 256 + threadIdx.x;   // float4 index, 1835008 total
    const float* src; bf16* dst; int off; float scale = 1.0f;
    if (i < 1048576)      { src = x;  dst = xb;              off = i; }
    else if (i < 1310720) { src = Wq; dst = wb;              off = i - 1048576; scale = qscale; }
    else if (i < 1572864) { src = Wk; dst = wb + (1u << 20); off = i - 1310720; }
    else                  { src = Wv; dst = wb + (2u << 20); off = i - 1572864; }
    float4 v = reinterpret_cast<const float4*>(src)[off];
    bf16x4 o;
    o[0] = (bf16)(v.x * scale); o[1] = (bf16)(v.y * scale);
    o[2] = (bf16)(v.z * scale); o[3] = (bf16)(v.w * scale);
    reinterpret_cast<bf16x4*>(dst)[off] = o;
}

// ---------------- fused QKV projection: y = x @ [Wq|Wk|Wv]^T ----------------
// 128x128 tiles (m97 structure), BK=64 -> 768 blocks = 3/CU, acc 4x4 per wave.
// CONFIRMED win vs 128x64 (R3/R5 delta attribution, ~13 us).
// LDS[row][cc] = global[row][cc ^ (row&7)] (8-elem chunks, conflict-free readback)
__global__ __launch_bounds__(256) void qkv_gemm(const bf16* __restrict__ xb,
                                                const bf16* __restrict__ wb,
                                                bf16* __restrict__ Qo,
                                                bf16* __restrict__ Ko,
                                                bf16* __restrict__ Vt) {
    const int n0 = blockIdx.x * 128;
    const int m0 = blockIdx.y * 128;

    __shared__ __align__(16) bf16 As[128 * 64];   // 16 KB
    __shared__ __align__(16) bf16 Bs[128 * 64];   // 16 KB

    const int t    = threadIdx.x;
    const int lane = t & 63;
    const int wid  = t >> 6;
    const int quad = lane >> 4;
    const int col  = lane & 15;
    const int wm   = wid & 1;      // M half (64)
    const int wn   = wid >> 1;     // N half (64)

    const int rsub = lane >> 3;
    const int csw  = ((lane & 7) ^ rsub) * 8;

    f32x4 acc[4][4] = {};

    const bf16* Ag = &xb[(size_t)(m0 + rsub) * 1024 + csw];
    const bf16* Bg = &wb[(size_t)(n0 + rsub) * 1024 + csw];

    for (int kc = 0; kc < 1024; kc += 64) {
        __syncthreads();
#pragma unroll
        for (int j = 0; j < 4; ++j) {
            const int c = wid * 4 + j;           // 16 A chunk-blocks (8 rows each)
            load_lds16(Ag + kc + (size_t)c * 8 * 1024, &As[c * 512]);
        }
#pragma unroll
        for (int j = 0; j < 4; ++j) {
            const int c = wid * 4 + j;           // 16 B chunk-blocks
            load_lds16(Bg + kc + (size_t)c * 8 * 1024, &Bs[c * 512]);
        }
        __syncthreads();

#pragma unroll
        for (int ks = 0; ks < 2; ++ks) {
            const int ca = ((ks * 4 + quad) ^ (col & 7)) * 8;
            bf16x8 a[4], b[4];
#pragma unroll
            for (int i = 0; i < 4; ++i)
                a[i] = *reinterpret_cast<const bf16x8*>(
                    &As[(wm * 64 + i * 16 + col) * 64 + ca]);
#pragma unroll
            for (int i = 0; i < 4; ++i)
                b[i] = *reinterpret_cast<const bf16x8*>(
                    &Bs[(wn * 64 + i * 16 + col) * 64 + ca]);
#pragma unroll
            for (int mt = 0; mt < 4; ++mt)
#pragma unroll
                for (int nt = 0; nt < 4; ++nt)
                    acc[mt][nt] = MFMA16(a[mt], b[nt], acc[mt][nt]);
        }
    }

    const int w = blockIdx.x >> 3;   // 8 x-blocks per 1024 outputs: 0=Q 1=K 2=V
#pragma unroll
    for (int mt = 0; mt < 4; ++mt) {
#pragma unroll
        for (int nt = 0; nt < 4; ++nt) {
#pragma unroll
            for (int r = 0; r < 4; ++r) {
                int m = m0 + wm * 64 + mt * 16 + quad * 4 + r;
                int n = n0 + wn * 64 + nt * 16 + col;
                int bb = m >> 11, s = m & 2047;
                int n1 = n & 1023;
                int h = n1 >> 6, d = n1 & 63;
                size_t bh = (size_t)(bb * 16 + h);
                bf16 v = (bf16)acc[mt][nt][r];
                if (w == 0)      Qo[(bh * 2048 + s) * 64 + d] = v;
                else if (w == 1) Ko[(bh * 2048 + s) * 64 + d] = v;
                else             Vt[(bh * 64 + d) * 2048 + s] = v;
            }
        }
    }
}

// ---------------- V suffix tile sums (parallel) ----------------
__global__ __launch_bounds__(256) void tail_kernel(const bf16* __restrict__ Vt,
                                                   float* __restrict__ Tail) {
    const int bh = blockIdx.x;
    const bf16* Vg = Vt + (size_t)bh * 64 * 2048;
    float* Tg = Tail + (size_t)bh * 33 * 64;

    __shared__ float ts[64 * 33];
    const int tid = threadIdx.x;

#pragma unroll
    for (int i = 0; i < 8; ++i) {
        int task = i * 256 + tid;          // 0..2047
        int d = task >> 5, tt = task & 31;
        const bf16* p = &Vg[(size_t)d * 2048 + tt * 64];
        float s = 0.0f;
#pragma unroll
        for (int j = 0; j < 8; ++j) {
            bf16x8 v = *reinterpret_cast<const bf16x8*>(p + j * 8);
#pragma unroll
            for (int e = 0; e < 8; ++e) s += (float)v[e];
        }
        ts[d * 33 + tt] = s;
    }
    __syncthreads();

    if (tid < 64) {
        const int d = tid;
        float s = 0.0f;
        Tg[32 * 64 + d] = 0.0f;
        for (int tt = 31; tt >= 1; --tt) {
            s += ts[d * 33 + tt];
            Tg[tt * 64 + d] = s;
        }
    }
}

// ---------------- attention ----------------
// R6-verified inner loop (2-way LDS-operand reuse, swapped QK, shared P,
// barrier-bounded staging) wrapped in a 2-tile outer loop: each block does
// q-tiles qtb=31-x (heavy) then qta=x (light) SEQUENTIALLY, reusing all
// registers and LDS. Per-block work = ntb+nta = 17 chunks for every x ->
// perfectly uniform, 512 blocks = 2 resident/CU, zero dispatch tail.
// Q pre-scaled by log2(e)/32. Multiplicative mask: masked score=0 ->
// p=exp2(0)=1, still counted; fully-masked tail via Tail suffix sums.
__global__ __launch_bounds__(256) void attn_kernel(const bf16* __restrict__ Q,
                                                   const bf16* __restrict__ K,
                                                   const bf16* __restrict__ Vt,
                                                   const float* __restrict__ Tail,
                                                   float* __restrict__ out) {
    const int b = blockIdx.z;
    const int h = blockIdx.y;

    const int t    = threadIdx.x;
    const int lane = t & 63;
    const int wid  = t >> 6;
    const int quad = lane >> 4;
    const int col  = lane & 15;
    const int qh   = wid & 1;     // q-half (32 rows) for both phases
    const int kh   = wid >> 1;    // key-half (QK) / d-half (PV)

    const int bh = b * 16 + h;
    const bf16* Qg = Q + (size_t)bh * 2048 * 64;
    const bf16* Kg = K + (size_t)bh * 2048 * 64;
    const bf16* Vg = Vt + (size_t)bh * 64 * 2048;

    __shared__ __align__(16) bf16 Ks[128 * 64];   // 16 KB: [key][d], swizzled
    __shared__ __align__(16) bf16 Vs[64 * 128];   // 16 KB: [d][key], swizzled
    __shared__ __align__(16) bf16 Ps[64 * 136];   // 17 KB: [q][key], shared

    bf16x8 ones;
#pragma unroll
    for (int i = 0; i < 8; ++i) ones[i] = (bf16)1.0f;

    // K staging: 16 chunk-blocks of 8 rows x 64; V staging: 16 chunk-blocks of 4 rows x 128
    const int rsubK = lane >> 3;
    const int cswK  = ((lane & 7) ^ rsubK) * 8;
    const int rV    = lane >> 4;
    const int ccV   = lane & 15;

    for (int pp = 0; pp < 2; ++pp) {
        const int qt = pp == 0 ? (31 - (int)blockIdx.x) : (int)blockIdx.x;
        const int q0 = qt * 64;
        const int np = (qt >> 1) + 1;      // 128-key chunks to process in-loop

        // Q frags: qf[qs][ks] for the wave's 2 q-subtiles
        bf16x8 qf[2][2];
#pragma unroll
        for (int qs = 0; qs < 2; ++qs)
#pragma unroll
            for (int ks = 0; ks < 2; ++ks)
                qf[qs][ks] = *reinterpret_cast<const bf16x8*>(
                    &Qg[(size_t)(q0 + qh * 32 + qs * 16 + col) * 64 + ks * 32 + quad * 8]);

        // init with fully-masked tail beyond 2*np tiles (p == 1 there)
        f32x4 o[2][2];
        f32x4 la[2];
        {
            const float tc = 64.0f * (float)(32 - 2 * np);
#pragma unroll
            for (int qs = 0; qs < 2; ++qs)
#pragma unroll
                for (int r = 0; r < 4; ++r) la[qs][r] = tc;
            const float* Tg = Tail + ((size_t)bh * 33 + 2 * np) * 64;
#pragma unroll
            for (int dt = 0; dt < 2; ++dt) {
                float tv = Tg[kh * 32 + dt * 16 + col];
#pragma unroll
                for (int qs = 0; qs < 2; ++qs)
#pragma unroll
                    for (int r = 0; r < 4; ++r) o[qs][dt][r] = tv;
            }
        }

        const int s0max = (np - 1) * 128;

        for (int s0 = 0; s0 < np * 128; s0 += 128) {
            __syncthreads();   // previous phase's LDS reads complete
#pragma unroll
            for (int jj = 0; jj < 4; ++jj) {
                const int c = wid * 4 + jj;
                load_lds16(&Kg[(size_t)(s0 + c * 8 + rsubK) * 64 + cswK], &Ks[c * 512]);
                const int d = c * 4 + rV;
                load_lds16(&Vg[(size_t)d * 2048 + s0 + ((ccV ^ (d & 15)) * 8)], &Vs[c * 512]);
            }
            __syncthreads();   // staging drained (vmcnt(0) before s_barrier)

            // QK (swapped): S^T for keys [kh*64..+64) x q [qh*32..+32)
            // sv[qs][nt][r] = S[key=s0+kh*64+nt*16+quad*4+r][q=q0+qh*32+qs*16+col]
            f32x4 sv[2][4] = {};
            __builtin_amdgcn_s_setprio(1);
#pragma unroll
            for (int ks = 0; ks < 2; ++ks) {
                const int ca = ((ks * 4 + quad) ^ (col & 7)) * 8;
#pragma unroll
                for (int nt = 0; nt < 4; ++nt) {
                    bf16x8 kb = *reinterpret_cast<const bf16x8*>(
                        &Ks[((kh * 4 + nt) * 16 + col) * 64 + ca]);
                    sv[0][nt] = MFMA16(kb, qf[0][ks], sv[0][nt]);
                    sv[1][nt] = MFMA16(kb, qf[1][ks], sv[1][nt]);
                }
            }
            __builtin_amdgcn_s_setprio(0);

            // multiplicative mask only on the last chunk (diagonal + dead upper)
            if (s0 == s0max) {
#pragma unroll
                for (int qs = 0; qs < 2; ++qs) {
                    const int qc = q0 + qh * 32 + qs * 16 + col;
#pragma unroll
                    for (int nt = 0; nt < 4; ++nt)
#pragma unroll
                        for (int r = 0; r < 4; ++r) {
                            int kidx = s0 + kh * 64 + nt * 16 + quad * 4 + r;
                            if (kidx > qc) sv[qs][nt][r] = 0.0f;
                        }
                }
            }

            // exp2 + pack 4 consecutive keys -> ds_write_b64 into shared P [q][key]
#pragma unroll
            for (int qs = 0; qs < 2; ++qs) {
                bf16* Pq = &Ps[(qh * 32 + qs * 16 + col) * 136 + kh * 64];
#pragma unroll
                for (int nt = 0; nt < 4; ++nt) {
                    bf16x4 pw;
#pragma unroll
                    for (int r = 0; r < 4; ++r)
                        pw[r] = (bf16)__builtin_amdgcn_exp2f(sv[qs][nt][r]);
                    *reinterpret_cast<bf16x4*>(&Pq[nt * 16 + quad * 4]) = pw;
                }
            }

            __syncthreads();   // P quadrants from all waves visible

            // PV: o[q-half qh][d-half kh] over all 128 keys; vb shared by 2 q-subs
            __builtin_amdgcn_s_setprio(1);
#pragma unroll
            for (int kg = 0; kg < 4; ++kg) {
                bf16x8 pa0 = *reinterpret_cast<const bf16x8*>(
                    &Ps[(qh * 32 + col) * 136 + kg * 32 + quad * 8]);
                bf16x8 pa1 = *reinterpret_cast<const bf16x8*>(
                    &Ps[(qh * 32 + 16 + col) * 136 + kg * 32 + quad * 8]);
                la[0] = MFMA16(pa0, ones, la[0]);
                la[1] = MFMA16(pa1, ones, la[1]);
#pragma unroll
                for (int dt = 0; dt < 2; ++dt) {
                    bf16x8 vb = *reinterpret_cast<const bf16x8*>(
                        &Vs[(kh * 32 + dt * 16 + col) * 128 + ((kg * 4 + quad) ^ col) * 8]);
                    o[0][dt] = MFMA16(pa0, vb, o[0][dt]);
                    o[1][dt] = MFMA16(pa1, vb, o[1][dt]);
                }
            }
            __builtin_amdgcn_s_setprio(0);
        }

#pragma unroll
        for (int qs = 0; qs < 2; ++qs) {
#pragma unroll
            for (int r = 0; r < 4; ++r) {
                int q = q0 + qh * 32 + qs * 16 + quad * 4 + r;
                float inv = __builtin_amdgcn_rcpf(la[qs][r]);
#pragma unroll
                for (int dt = 0; dt < 2; ++dt) {
                    int d = kh * 32 + dt * 16 + col;
                    out[((size_t)b * 2048 + q) * 1024 + h * 64 + d] = o[qs][dt][r] * inv;
                }
            }
        }
    }
}

extern "C" void kernel_launch(void* const* d_in, const int* in_sizes, int n_in,
                              void* d_out, int out_size, void* d_ws, size_t ws_size,
                              hipStream_t stream) {
    const float* x  = (const float*)d_in[0];
    const float* Wq = (const float*)d_in[1];
    const float* Wk = (const float*)d_in[2];
    const float* Wv = (const float*)d_in[3];
    float* out = (float*)d_out;

    char* ws = (char*)d_ws;
    bf16*  xb   = (bf16*)(ws);                        // 8 MB
    bf16*  wb   = (bf16*)(ws + (size_t)(8  << 20));   // 6 MB [Wq|Wk|Wv]
    bf16*  Qb   = (bf16*)(ws + (size_t)(14 << 20));   // 8 MB [B,H,S,D] (pre-scaled)
    bf16*  Kb   = (bf16*)(ws + (size_t)(22 << 20));   // 8 MB [B,H,S,D]
    bf16*  Vtb  = (bf16*)(ws + (size_t)(30 << 20));   // 8 MB [B,H,D,S]
    float* Tail = (float*)(ws + (size_t)(38 << 20));  // 264 KB

    const float QSCALE = 1.44269504088896f / 32.0f;   // log2(e)/sqrt(E)

    cast_all<<<7168, 256, 0, stream>>>(x, Wq, Wk, Wv, xb, wb, QSCALE);

    qkv_gemm<<<dim3(24, 32), 256, 0, stream>>>(xb, wb, Qb, Kb, Vtb);

    tail_kernel<<<32, 256, 0, stream>>>(Vtb, Tail);

    attn_kernel<<<dim3(16, 16, 2), 256, 0, stream>>>(Qb, Kb, Vtb, Tail, out);
}